// Round 9
// baseline (281.970 us; speedup 1.0000x reference)
//
#include <hip/hip_runtime.h>
#include <hip/hip_bf16.h>
#include <hip/hip_fp16.h>

#define NN 100000
#define NE 1600000
#define NG 5000
#define FIN 11
#define HID 128
#define NC 19

#define NBK 196          // buckets for CSR build
#define BKSH 9           // bucket = dst >> 9
#define BKMASK 511
#define BCAP 10240       // p1 bucket capacity (mean 8163, +23 sigma)
#define CCAP 12288       // csr per-bucket region (real <=10240 + pad <=1536)

typedef _Float16 f16x8 __attribute__((ext_vector_type(8)));
typedef float f32x4 __attribute__((ext_vector_type(4)));

// ---------- CSR build ----------

__global__ __launch_bounds__(1024) void k_p1scatter(const int* __restrict__ ei,
                                                    int* __restrict__ gcur, unsigned int* __restrict__ p1) {
    __shared__ int hist[NBK];
    __shared__ int base[NBK];
    __shared__ int lrank[NBK];
    int t = threadIdx.x;
    if (t < NBK) { hist[t] = 0; lrank[t] = 0; }
    __syncthreads();

    int e0 = blockIdx.x * 4096 + t * 4;
    int sr[4], dr[4], bk[4];
    if (e0 + 3 < NE) {
        int4 s4 = *(const int4*)(ei + e0);
        int4 d4 = *(const int4*)(ei + NE + e0);
        sr[0] = s4.x; sr[1] = s4.y; sr[2] = s4.z; sr[3] = s4.w;
        dr[0] = d4.x; dr[1] = d4.y; dr[2] = d4.z; dr[3] = d4.w;
        #pragma unroll
        for (int k = 0; k < 4; ++k) { bk[k] = dr[k] >> BKSH; atomicAdd(&hist[bk[k]], 1); }
    } else {
        #pragma unroll
        for (int k = 0; k < 4; ++k) {
            int e = e0 + k;
            if (e < NE) { sr[k] = ei[e]; dr[k] = ei[NE + e]; bk[k] = dr[k] >> BKSH; atomicAdd(&hist[bk[k]], 1); }
            else bk[k] = -1;
        }
    }
    __syncthreads();
    if (t < NBK && hist[t] > 0)
        base[t] = t * BCAP + atomicAdd(&gcur[t], hist[t]);
    __syncthreads();
    #pragma unroll
    for (int k = 0; k < 4; ++k) {
        if (bk[k] >= 0) {
            int slot = atomicAdd(&lrank[bk[k]], 1);
            p1[base[bk[k]] + slot] = (unsigned int)sr[k] | ((unsigned int)(dr[k] & BKMASK) << 17);
        }
    }
}

// Per bucket (512 nodes): degree count -> padded scan -> meta/dis -> exact placement + pad-to-4.
__global__ __launch_bounds__(1024) void k_p2fill(const unsigned int* __restrict__ p1,
                                                 const int* __restrict__ gcur,
                                                 unsigned int* __restrict__ meta, int* __restrict__ csr,
                                                 float* __restrict__ dis) {
    __shared__ int cnt[512];
    __shared__ int pf[512];
    __shared__ int cur[512];
    __shared__ int wsum[8];
    int bkt = blockIdx.x;
    int t = threadIdx.x;
    int v0 = bkt << BKSH;
    int nb = NN - v0; if (nb > 512) nb = 512;
    unsigned int gb = (unsigned int)bkt * CCAP;
    if (t < 512) { cnt[t] = 0; cur[t] = 0; }
    __syncthreads();
    int count = gcur[bkt]; if (count > BCAP) count = BCAP;
    const unsigned int* reg = p1 + (size_t)bkt * BCAP;
    for (int i = t; i < count; i += 1024)
        atomicAdd(&cnt[reg[i] >> 17], 1);
    __syncthreads();
    int c = 0, pc = 0, val = 0;
    int lane = t & 63, w = t >> 6;
    if (t < 512) {
        c = cnt[t];
        pc = (c + 3) & ~3;
        val = pc;
        #pragma unroll
        for (int off = 1; off < 64; off <<= 1) {
            int n = __shfl_up(val, off, 64);
            if (lane >= off) val += n;
        }
        if (lane == 63) wsum[w] = val;
    }
    __syncthreads();
    if (w == 0) {
        int s = (lane < 8) ? wsum[lane] : 0;
        #pragma unroll
        for (int off = 1; off < 8; off <<= 1) {
            int n = __shfl_up(s, off, 64);
            if (lane >= off) s += n;
        }
        if (lane < 8) wsum[lane] = s;
    }
    __syncthreads();
    if (t < 512) {
        int wbase = (w == 0) ? 0 : wsum[w - 1];
        int excl = wbase + val - pc;
        pf[t] = excl;
        if (t < nb) {
            meta[v0 + t] = ((gb + (unsigned int)excl) << 9) | (unsigned int)(pc >> 2);
            dis[v0 + t] = rsqrtf((float)c + 1.0f);
        }
    }
    __syncthreads();
    for (int i = t; i < count; i += 1024) {
        unsigned int u = reg[i];
        int dl = u >> 17;
        int off2 = atomicAdd(&cur[dl], 1);
        csr[gb + pf[dl] + off2] = (int)(u & 0x1FFFFu);
    }
    if (t < nb) {
        int b0 = gb + pf[t];
        for (int k = c; k < pc; ++k) csr[b0 + k] = NN;   // pad edges -> zero row
    }
}

// ---------- fused setup: prescale | gstart | packW(W2) | wfuse | zero pad row ----------

__global__ __launch_bounds__(256) void k_setup(const float* __restrict__ x, const float* __restrict__ dis,
                                               const int* __restrict__ batch,
                                               const float* __restrict__ W2, const float* __restrict__ W3,
                                               const float* __restrict__ b3, const float* __restrict__ Wl,
                                               const float* __restrict__ bl,
                                               _Float16* __restrict__ xsc, int* __restrict__ gstart,
                                               _Float16* __restrict__ Wp2, float* __restrict__ Wf,
                                               float* __restrict__ bf,
                                               _Float16* __restrict__ Ht) {
    int b = blockIdx.x, t = threadIdx.x;
    if (b < 6251) {
        int i = b * 256 + t;
        if (i < (NN + 1) * 16) {
            int v = i >> 4, c = i & 15;
            float val = (v < NN && c < FIN) ? x[v * FIN + c] * dis[v] : 0.f;
            xsc[i] = (_Float16)val;
        }
    } else if (b < 6271) {
        int g = (b - 6251) * 256 + t;
        if (g > NG) return;
        int lo = 0, hi = NN;
        while (lo < hi) {
            int mid = (lo + hi) >> 1;
            if (batch[mid] < g) lo = mid + 1; else hi = mid;
        }
        gstart[g] = lo;
    } else if (b < 6279) {
        int t2 = (b - 6271) * 256 + t;
        int lane = t2 & 63;
        int tile = t2 >> 6;
        int kb = tile >> 3, ct = tile & 7;
        int kbase = kb * 32 + (lane >> 4) * 8;
        int col = ct * 16 + (lane & 15);
        f16x8 v;
        #pragma unroll
        for (int e = 0; e < 8; ++e) v[e] = (_Float16)W2[(kbase + e) * HID + col];
        *(f16x8*)&Wp2[(size_t)t2 * 8] = v;
    } else if (b < 6312) {
        int i = (b - 6279) * 4 + (t >> 6);
        int tc = t & 63;
        if (tc >= NC || i > HID) return;
        if (i < HID) {
            float a = 0.f;
            #pragma unroll 4
            for (int k = 0; k < HID; ++k) a += W3[i * HID + k] * Wl[k * NC + tc];
            Wf[i * NC + tc] = a;
        } else {
            float a = bl[tc];
            #pragma unroll 4
            for (int k = 0; k < HID; ++k) a += b3[k] * Wl[k * NC + tc];
            bf[tc] = a;
        }
    } else {
        if (t < HID) Ht[(size_t)NN * HID + t] = (_Float16)0.f;
    }
}

// ---------- layer 1 fused: agg11 + gemm11 ----------

__global__ __launch_bounds__(256) void k_l1(const _Float16* __restrict__ xsc,
                                            const unsigned int* __restrict__ meta,
                                            const int* __restrict__ csr, const float* __restrict__ dis,
                                            const float* __restrict__ W1, const float* __restrict__ b1,
                                            _Float16* __restrict__ out16) {
    __shared__ float Ws[FIN][HID];
    __shared__ float Xs[16][17];
    int t = threadIdx.x;
    int row0 = blockIdx.x * 16;
    for (int idx = t; idx < FIN * HID; idx += 256) Ws[idx / HID][idx % HID] = W1[idx];

    int wave = t >> 6, lane = t & 63;
    int erel = lane >> 4, c = lane & 15;
    #pragma unroll
    for (int i = 0; i < 4; ++i) {
        int v = row0 + wave * 4 + i;
        unsigned int m = meta[v];
        int beg = (int)(m >> 9);
        int pend = beg + (int)((m & 511u) << 2);
        float accA = 0.f, accB = 0.f;
        int e = beg;
        for (; e + 8 <= pend; e += 8) {
            int s0 = csr[e + erel], s1 = csr[e + 4 + erel];
            accA += (float)xsc[s0 * 16 + c];
            accB += (float)xsc[s1 * 16 + c];
        }
        if (e < pend) accA += (float)xsc[csr[e + erel] * 16 + c];
        float a = accA + accB;
        a += __shfl_xor(a, 16);
        a += __shfl_xor(a, 32);
        if (erel == 0) {
            a += (float)xsc[v * 16 + c];
            Xs[wave * 4 + i][c] = a * dis[v];
        }
    }
    __syncthreads();
    int cc = t & (HID - 1);
    int rg = t >> 7;
    #pragma unroll
    for (int i = 0; i < 8; ++i) {
        int r = rg * 8 + i;
        int row = row0 + r;
        float a = b1[cc];
        #pragma unroll
        for (int k = 0; k < FIN; ++k) a += Xs[r][k] * Ws[k][cc];
        a = fmaxf(a, 0.f);
        out16[(size_t)row * HID + cc] = (_Float16)(a * dis[row]);
    }
}

// ---------- aggregation (layer 2) ----------

__global__ __launch_bounds__(256) void k_agg16(const _Float16* __restrict__ Ht,
                                               const unsigned int* __restrict__ meta,
                                               const int* __restrict__ csr, const float* __restrict__ dis,
                                               _Float16* __restrict__ out16) {
    int wid = threadIdx.x >> 6;
    int lane = threadIdx.x & 63;
    int v = blockIdx.x * 4 + wid;
    if (v >= NN) return;
    int erel = lane >> 4;
    int c8 = lane & 15;
    const _Float16* bp = Ht + (size_t)c8 * 8;
    unsigned int m = meta[v];
    int beg = (int)(m >> 9);
    int pend = beg + (int)((m & 511u) << 2);
    float acc0[8] = {}, acc1[8] = {};
    int e = beg;
    for (; e + 16 <= pend; e += 16) {
        int s0 = csr[e + erel];
        int s1 = csr[e + 4 + erel];
        int s2 = csr[e + 8 + erel];
        int s3 = csr[e + 12 + erel];
        f16x8 h0 = *(const f16x8*)(bp + (size_t)s0 * HID);
        f16x8 h1 = *(const f16x8*)(bp + (size_t)s1 * HID);
        f16x8 h2 = *(const f16x8*)(bp + (size_t)s2 * HID);
        f16x8 h3 = *(const f16x8*)(bp + (size_t)s3 * HID);
        #pragma unroll
        for (int j = 0; j < 8; ++j) {
            acc0[j] += (float)h0[j] + (float)h2[j];
            acc1[j] += (float)h1[j] + (float)h3[j];
        }
    }
    for (; e < pend; e += 4) {
        int s = csr[e + erel];
        f16x8 h = *(const f16x8*)(bp + (size_t)s * HID);
        #pragma unroll
        for (int j = 0; j < 8; ++j) acc0[j] += (float)h[j];
    }
    #pragma unroll
    for (int j = 0; j < 8; ++j) {
        float s = acc0[j] + acc1[j];
        s += __shfl_xor(s, 16);
        s += __shfl_xor(s, 32);
        acc0[j] = s;
    }
    if (erel == 0) {
        f16x8 sh = *(const f16x8*)(bp + (size_t)v * HID);
        float dv = dis[v];
        f16x8 o;
        #pragma unroll
        for (int j = 0; j < 8; ++j) o[j] = (_Float16)((acc0[j] + (float)sh[j]) * dv);
        *(f16x8*)(out16 + (size_t)v * HID + c8 * 8) = o;
    }
}

// ---------- MFMA GEMM (layer 2) ----------

__global__ __launch_bounds__(256) void k_gemm128m(const _Float16* __restrict__ X,
                                                  const _Float16* __restrict__ Wp,
                                                  const float* __restrict__ bias,
                                                  const float* __restrict__ dis,
                                                  _Float16* __restrict__ out) {
    int wave = threadIdx.x >> 6, lane = threadIdx.x & 63;
    int row0 = blockIdx.x * 128 + wave * 32;
    int rA = lane & 15, kg = lane >> 4;

    f32x4 acc[2][8];
    #pragma unroll
    for (int s = 0; s < 2; ++s)
        #pragma unroll
        for (int c = 0; c < 8; ++c)
            acc[s][c] = {0.f, 0.f, 0.f, 0.f};

    int r0c = row0 + rA;      if (r0c > NN - 1) r0c = NN - 1;
    int r1c = row0 + 16 + rA; if (r1c > NN - 1) r1c = NN - 1;
    const _Float16* xp0 = X + (size_t)r0c * HID + kg * 8;
    const _Float16* xp1 = X + (size_t)r1c * HID + kg * 8;

    #pragma unroll
    for (int kb = 0; kb < 4; ++kb) {
        f16x8 a0 = *(const f16x8*)(xp0 + kb * 32);
        f16x8 a1 = *(const f16x8*)(xp1 + kb * 32);
        #pragma unroll
        for (int ct = 0; ct < 8; ++ct) {
            f16x8 b = *(const f16x8*)&Wp[(size_t)((kb * 8 + ct) * 64 + lane) * 8];
            acc[0][ct] = __builtin_amdgcn_mfma_f32_16x16x32_f16(a0, b, acc[0][ct], 0, 0, 0);
            acc[1][ct] = __builtin_amdgcn_mfma_f32_16x16x32_f16(a1, b, acc[1][ct], 0, 0, 0);
        }
    }

    int c15 = lane & 15;
    #pragma unroll
    for (int s = 0; s < 2; ++s) {
        int rbase = row0 + s * 16 + kg * 4;
        float dv[4];
        #pragma unroll
        for (int r = 0; r < 4; ++r) {
            int rr = rbase + r; if (rr > NN - 1) rr = NN - 1;
            dv[r] = dis[rr];
        }
        #pragma unroll
        for (int ct = 0; ct < 8; ++ct) {
            int col = ct * 16 + c15;
            float bb = bias[col];
            #pragma unroll
            for (int r = 0; r < 4; ++r) {
                int rr = rbase + r;
                if (rr < NN) {
                    float v = fmaxf(acc[s][ct][r] + bb, 0.f) * dv[r];
                    out[(size_t)rr * HID + col] = (_Float16)v;
                }
            }
        }
    }
}

// ---------- fused layer-3 agg + mean-pool + linear ----------
// One wave per graph: gacc = sum_v dis_v * ( sum_{s in N(v)} t_s + t_v ), t = prescaled Ht.
// out = (gacc/n) @ Wf + bf.
__global__ __launch_bounds__(256) void k_aggpool(const _Float16* __restrict__ Ht,
                                                 const unsigned int* __restrict__ meta,
                                                 const int* __restrict__ csr, const float* __restrict__ dis,
                                                 const int* __restrict__ gstart,
                                                 const float* __restrict__ Wf, const float* __restrict__ bf,
                                                 float* __restrict__ out) {
    __shared__ float ps[4][HID];
    int wid = threadIdx.x >> 6, lane = threadIdx.x & 63;
    int g = blockIdx.x * 4 + wid;          // grid = NG/4 exactly
    int erel = lane >> 4, c8 = lane & 15;
    const _Float16* bp = Ht + (size_t)c8 * 8;
    int nbeg = gstart[g], nend = gstart[g + 1];
    float gacc[8] = {};
    for (int v = nbeg; v < nend; ++v) {
        unsigned int m = meta[v];
        int beg = (int)(m >> 9);
        int pend = beg + (int)((m & 511u) << 2);
        float dv = dis[v];
        float va[8] = {}, vb[8] = {};
        for (int e = beg; e < pend; e += 8) {
            int i1 = e + erel;
            int i2 = e + 4 + erel;
            int s1 = csr[i1];
            int s2 = (i2 < pend) ? csr[i2] : NN;
            f16x8 h1 = *(const f16x8*)(bp + (size_t)s1 * HID);
            f16x8 h2 = *(const f16x8*)(bp + (size_t)s2 * HID);
            #pragma unroll
            for (int j = 0; j < 8; ++j) { va[j] += (float)h1[j]; vb[j] += (float)h2[j]; }
        }
        if (erel == 0) {                    // self loop: + t_v (prescaled row)
            f16x8 hv = *(const f16x8*)(bp + (size_t)v * HID);
            #pragma unroll
            for (int j = 0; j < 8; ++j) va[j] += (float)hv[j];
        }
        #pragma unroll
        for (int j = 0; j < 8; ++j) gacc[j] += dv * (va[j] + vb[j]);
    }
    #pragma unroll
    for (int j = 0; j < 8; ++j) {
        float s = gacc[j];
        s += __shfl_xor(s, 16);
        s += __shfl_xor(s, 32);
        gacc[j] = s;
    }
    float inv = 1.f / fmaxf((float)(nend - nbeg), 1.f);
    if (erel == 0) {
        #pragma unroll
        for (int j = 0; j < 8; ++j) ps[wid][c8 * 8 + j] = gacc[j] * inv;
    }
    __syncthreads();
    if (lane < NC) {
        float a = bf[lane];
        #pragma unroll 4
        for (int k = 0; k < HID; ++k) a += ps[wid][k] * Wf[k * NC + lane];
        out[g * NC + lane] = a;
    }
}

// ---------- launch ----------

extern "C" void kernel_launch(void* const* d_in, const int* in_sizes, int n_in,
                              void* d_out, int out_size, void* d_ws, size_t ws_size,
                              hipStream_t stream) {
    const float* x   = (const float*)d_in[0];
    const int* ei    = (const int*)d_in[1];
    const int* batch = (const int*)d_in[2];
    const float* W1 = (const float*)d_in[3];
    const float* b1 = (const float*)d_in[4];
    const float* W2 = (const float*)d_in[5];
    const float* b2 = (const float*)d_in[6];
    const float* W3 = (const float*)d_in[7];
    const float* b3 = (const float*)d_in[8];
    const float* Wl = (const float*)d_in[9];
    const float* bl = (const float*)d_in[10];
    float* out = (float*)d_out;

    char* ws = (char*)d_ws;
    size_t off = 0;
    auto alloc = [&](size_t bytes) -> void* {
        void* p = ws + off;
        off += (bytes + 255) & ~(size_t)255;
        return p;
    };
    float*        dis    = (float*)alloc((size_t)NN * 4);
    unsigned int* meta   = (unsigned int*)alloc((size_t)NN * 4);
    int*          csr    = (int*)alloc((size_t)NBK * CCAP * 4);
    unsigned int* p1     = (unsigned int*)alloc((size_t)NBK * BCAP * 4);
    int*          gcur   = (int*)alloc(NBK * 4);
    int*          gstart = (int*)alloc((size_t)(NG + 1) * 4);
    _Float16*     xsc    = (_Float16*)alloc((size_t)(NN + 1) * 16 * 2);
    _Float16*     Wp2    = (_Float16*)alloc((size_t)HID * HID * 2);
    float*        Wf     = (float*)alloc((size_t)HID * NC * 4);
    float*        bf     = (float*)alloc(NC * 4);
    _Float16*     Ht     = (_Float16*)alloc((size_t)(NN + 1) * HID * 2);
    _Float16*     tb16   = (_Float16*)alloc((size_t)(NN + 1) * HID * 2);
    (void)ws_size; (void)in_sizes; (void)n_in; (void)out_size;

    hipMemsetAsync(gcur, 0, NBK * 4, stream);

    // CSR build
    k_p1scatter<<<(NE + 4095) / 4096, 1024, 0, stream>>>(ei, gcur, p1);
    k_p2fill<<<NBK, 1024, 0, stream>>>(p1, gcur, meta, csr, dis);

    // fused setup (needs dis)
    k_setup<<<6313, 256, 0, stream>>>(x, dis, batch, W2, W3, b3, Wl, bl,
                                      xsc, gstart, Wp2, Wf, bf, Ht);

    // layer 1 (fused agg + gemm) -> Ht (prescaled fp16)
    k_l1<<<NN / 16, 256, 0, stream>>>(xsc, meta, csr, dis, W1, b1, Ht);

    // layer 2: agg -> tb16, MFMA GEMM -> Ht (prescaled)
    k_agg16<<<(NN + 3) / 4, 256, 0, stream>>>(Ht, meta, csr, dis, tb16);
    k_gemm128m<<<(NN + 127) / 128, 256, 0, stream>>>(tb16, Wp2, b2, dis, Ht);

    // layer 3 + pool + linear fused
    k_aggpool<<<NG / 4, 256, 0, stream>>>(Ht, meta, csr, dis, gstart, Wf, bf, out);
}

// Round 10
// 260.171 us; speedup vs baseline: 1.0838x; 1.0838x over previous
//
#include <hip/hip_runtime.h>
#include <hip/hip_bf16.h>
#include <hip/hip_fp16.h>

#define NN 100000
#define NE 1600000
#define NG 5000
#define FIN 11
#define HID 128
#define NC 19

#define NBK 196          // buckets for CSR build
#define BKSH 9           // bucket = dst >> 9
#define BKMASK 511
#define BCAP 10240       // p1 bucket capacity (mean 8163, +23 sigma)
#define CCAP 12288       // csr per-bucket region (real <=10240 + pad <=1536)

typedef _Float16 f16x8 __attribute__((ext_vector_type(8)));
typedef float f32x4 __attribute__((ext_vector_type(4)));

// ---------- CSR build ----------

__global__ __launch_bounds__(1024) void k_p1scatter(const int* __restrict__ ei,
                                                    int* __restrict__ gcur, unsigned int* __restrict__ p1) {
    __shared__ int hist[NBK];
    __shared__ int base[NBK];
    __shared__ int lrank[NBK];
    int t = threadIdx.x;
    if (t < NBK) { hist[t] = 0; lrank[t] = 0; }
    __syncthreads();

    int e0 = blockIdx.x * 4096 + t * 4;
    int sr[4], dr[4], bk[4];
    if (e0 + 3 < NE) {
        int4 s4 = *(const int4*)(ei + e0);
        int4 d4 = *(const int4*)(ei + NE + e0);
        sr[0] = s4.x; sr[1] = s4.y; sr[2] = s4.z; sr[3] = s4.w;
        dr[0] = d4.x; dr[1] = d4.y; dr[2] = d4.z; dr[3] = d4.w;
        #pragma unroll
        for (int k = 0; k < 4; ++k) { bk[k] = dr[k] >> BKSH; atomicAdd(&hist[bk[k]], 1); }
    } else {
        #pragma unroll
        for (int k = 0; k < 4; ++k) {
            int e = e0 + k;
            if (e < NE) { sr[k] = ei[e]; dr[k] = ei[NE + e]; bk[k] = dr[k] >> BKSH; atomicAdd(&hist[bk[k]], 1); }
            else bk[k] = -1;
        }
    }
    __syncthreads();
    if (t < NBK && hist[t] > 0)
        base[t] = t * BCAP + atomicAdd(&gcur[t], hist[t]);
    __syncthreads();
    #pragma unroll
    for (int k = 0; k < 4; ++k) {
        if (bk[k] >= 0) {
            int slot = atomicAdd(&lrank[bk[k]], 1);
            p1[base[bk[k]] + slot] = (unsigned int)sr[k] | ((unsigned int)(dr[k] & BKMASK) << 17);
        }
    }
}

// Per bucket (512 nodes): degree count -> padded scan -> meta/dis -> exact placement + pad-to-4.
__global__ __launch_bounds__(1024) void k_p2fill(const unsigned int* __restrict__ p1,
                                                 const int* __restrict__ gcur,
                                                 unsigned int* __restrict__ meta, int* __restrict__ csr,
                                                 float* __restrict__ dis) {
    __shared__ int cnt[512];
    __shared__ int pf[512];
    __shared__ int cur[512];
    __shared__ int wsum[8];
    int bkt = blockIdx.x;
    int t = threadIdx.x;
    int v0 = bkt << BKSH;
    int nb = NN - v0; if (nb > 512) nb = 512;
    unsigned int gb = (unsigned int)bkt * CCAP;
    if (t < 512) { cnt[t] = 0; cur[t] = 0; }
    __syncthreads();
    int count = gcur[bkt]; if (count > BCAP) count = BCAP;
    const unsigned int* reg = p1 + (size_t)bkt * BCAP;
    for (int i = t; i < count; i += 1024)
        atomicAdd(&cnt[reg[i] >> 17], 1);
    __syncthreads();
    int c = 0, pc = 0, val = 0;
    int lane = t & 63, w = t >> 6;
    if (t < 512) {
        c = cnt[t];
        pc = (c + 3) & ~3;
        val = pc;
        #pragma unroll
        for (int off = 1; off < 64; off <<= 1) {
            int n = __shfl_up(val, off, 64);
            if (lane >= off) val += n;
        }
        if (lane == 63) wsum[w] = val;
    }
    __syncthreads();
    if (w == 0) {
        int s = (lane < 8) ? wsum[lane] : 0;
        #pragma unroll
        for (int off = 1; off < 8; off <<= 1) {
            int n = __shfl_up(s, off, 64);
            if (lane >= off) s += n;
        }
        if (lane < 8) wsum[lane] = s;
    }
    __syncthreads();
    if (t < 512) {
        int wbase = (w == 0) ? 0 : wsum[w - 1];
        int excl = wbase + val - pc;
        pf[t] = excl;
        if (t < nb) {
            meta[v0 + t] = ((gb + (unsigned int)excl) << 9) | (unsigned int)(pc >> 2);
            dis[v0 + t] = rsqrtf((float)c + 1.0f);
        }
    }
    __syncthreads();
    for (int i = t; i < count; i += 1024) {
        unsigned int u = reg[i];
        int dl = u >> 17;
        int off2 = atomicAdd(&cur[dl], 1);
        csr[gb + pf[dl] + off2] = (int)(u & 0x1FFFFu);
    }
    if (t < nb) {
        int b0 = gb + pf[t];
        for (int k = c; k < pc; ++k) csr[b0 + k] = NN;   // pad edges -> zero row
    }
}

// ---------- fused setup: prescale | gstart | packW(W2) | wfuse | zero pad row ----------

__global__ __launch_bounds__(256) void k_setup(const float* __restrict__ x, const float* __restrict__ dis,
                                               const int* __restrict__ batch,
                                               const float* __restrict__ W2, const float* __restrict__ W3,
                                               const float* __restrict__ b3, const float* __restrict__ Wl,
                                               const float* __restrict__ bl,
                                               _Float16* __restrict__ xsc, int* __restrict__ gstart,
                                               _Float16* __restrict__ Wp2, float* __restrict__ Wf,
                                               float* __restrict__ bf,
                                               _Float16* __restrict__ Ht) {
    int b = blockIdx.x, t = threadIdx.x;
    if (b < 6251) {
        int i = b * 256 + t;
        if (i < (NN + 1) * 16) {
            int v = i >> 4, c = i & 15;
            float val = (v < NN && c < FIN) ? x[v * FIN + c] * dis[v] : 0.f;
            xsc[i] = (_Float16)val;
        }
    } else if (b < 6271) {
        int g = (b - 6251) * 256 + t;
        if (g > NG) return;
        int lo = 0, hi = NN;
        while (lo < hi) {
            int mid = (lo + hi) >> 1;
            if (batch[mid] < g) lo = mid + 1; else hi = mid;
        }
        gstart[g] = lo;
    } else if (b < 6279) {
        int t2 = (b - 6271) * 256 + t;
        int lane = t2 & 63;
        int tile = t2 >> 6;
        int kb = tile >> 3, ct = tile & 7;
        int kbase = kb * 32 + (lane >> 4) * 8;
        int col = ct * 16 + (lane & 15);
        f16x8 v;
        #pragma unroll
        for (int e = 0; e < 8; ++e) v[e] = (_Float16)W2[(kbase + e) * HID + col];
        *(f16x8*)&Wp2[(size_t)t2 * 8] = v;
    } else if (b < 6312) {
        int i = (b - 6279) * 4 + (t >> 6);
        int tc = t & 63;
        if (tc >= NC || i > HID) return;
        if (i < HID) {
            float a = 0.f;
            #pragma unroll 4
            for (int k = 0; k < HID; ++k) a += W3[i * HID + k] * Wl[k * NC + tc];
            Wf[i * NC + tc] = a;
        } else {
            float a = bl[tc];
            #pragma unroll 4
            for (int k = 0; k < HID; ++k) a += b3[k] * Wl[k * NC + tc];
            bf[tc] = a;
        }
    } else {
        if (t < HID) Ht[(size_t)NN * HID + t] = (_Float16)0.f;
    }
}

// ---------- layer 1 fused: agg11 + gemm11 ----------

__global__ __launch_bounds__(256) void k_l1(const _Float16* __restrict__ xsc,
                                            const unsigned int* __restrict__ meta,
                                            const int* __restrict__ csr, const float* __restrict__ dis,
                                            const float* __restrict__ W1, const float* __restrict__ b1,
                                            _Float16* __restrict__ out16) {
    __shared__ float Ws[FIN][HID];
    __shared__ float Xs[16][17];
    int t = threadIdx.x;
    int row0 = blockIdx.x * 16;
    for (int idx = t; idx < FIN * HID; idx += 256) Ws[idx / HID][idx % HID] = W1[idx];

    int wave = t >> 6, lane = t & 63;
    int erel = lane >> 4, c = lane & 15;
    #pragma unroll
    for (int i = 0; i < 4; ++i) {
        int v = row0 + wave * 4 + i;
        unsigned int m = meta[v];
        int beg = (int)(m >> 9);
        int pend = beg + (int)((m & 511u) << 2);
        float accA = 0.f, accB = 0.f;
        int e = beg;
        for (; e + 8 <= pend; e += 8) {
            int s0 = csr[e + erel], s1 = csr[e + 4 + erel];
            accA += (float)xsc[s0 * 16 + c];
            accB += (float)xsc[s1 * 16 + c];
        }
        if (e < pend) accA += (float)xsc[csr[e + erel] * 16 + c];
        float a = accA + accB;
        a += __shfl_xor(a, 16);
        a += __shfl_xor(a, 32);
        if (erel == 0) {
            a += (float)xsc[v * 16 + c];
            Xs[wave * 4 + i][c] = a * dis[v];
        }
    }
    __syncthreads();
    int cc = t & (HID - 1);
    int rg = t >> 7;
    #pragma unroll
    for (int i = 0; i < 8; ++i) {
        int r = rg * 8 + i;
        int row = row0 + r;
        float a = b1[cc];
        #pragma unroll
        for (int k = 0; k < FIN; ++k) a += Xs[r][k] * Ws[k][cc];
        a = fmaxf(a, 0.f);
        out16[(size_t)row * HID + cc] = (_Float16)(a * dis[row]);
    }
}

// ---------- aggregation (layers 2,3) ----------
// out16[v] = fp16( dis[v] * ( sum Ht[s] + Ht[v] ) ); padded CSR, zero row at NN.
__global__ __launch_bounds__(256) void k_agg16(const _Float16* __restrict__ Ht,
                                               const unsigned int* __restrict__ meta,
                                               const int* __restrict__ csr, const float* __restrict__ dis,
                                               _Float16* __restrict__ out16) {
    int wid = threadIdx.x >> 6;
    int lane = threadIdx.x & 63;
    int v = blockIdx.x * 4 + wid;
    if (v >= NN) return;
    int erel = lane >> 4;
    int c8 = lane & 15;
    const _Float16* bp = Ht + (size_t)c8 * 8;
    unsigned int m = meta[v];
    int beg = (int)(m >> 9);
    int pend = beg + (int)((m & 511u) << 2);
    float acc0[8] = {}, acc1[8] = {};
    int e = beg;
    for (; e + 16 <= pend; e += 16) {
        int s0 = csr[e + erel];
        int s1 = csr[e + 4 + erel];
        int s2 = csr[e + 8 + erel];
        int s3 = csr[e + 12 + erel];
        f16x8 h0 = *(const f16x8*)(bp + (size_t)s0 * HID);
        f16x8 h1 = *(const f16x8*)(bp + (size_t)s1 * HID);
        f16x8 h2 = *(const f16x8*)(bp + (size_t)s2 * HID);
        f16x8 h3 = *(const f16x8*)(bp + (size_t)s3 * HID);
        #pragma unroll
        for (int j = 0; j < 8; ++j) {
            acc0[j] += (float)h0[j] + (float)h2[j];
            acc1[j] += (float)h1[j] + (float)h3[j];
        }
    }
    for (; e < pend; e += 4) {
        int s = csr[e + erel];
        f16x8 h = *(const f16x8*)(bp + (size_t)s * HID);
        #pragma unroll
        for (int j = 0; j < 8; ++j) acc0[j] += (float)h[j];
    }
    #pragma unroll
    for (int j = 0; j < 8; ++j) {
        float s = acc0[j] + acc1[j];
        s += __shfl_xor(s, 16);
        s += __shfl_xor(s, 32);
        acc0[j] = s;
    }
    if (erel == 0) {
        f16x8 sh = *(const f16x8*)(bp + (size_t)v * HID);
        float dv = dis[v];
        f16x8 o;
        #pragma unroll
        for (int j = 0; j < 8; ++j) o[j] = (_Float16)((acc0[j] + (float)sh[j]) * dv);
        *(f16x8*)(out16 + (size_t)v * HID + c8 * 8) = o;
    }
}

// ---------- MFMA GEMM (layer 2) ----------

__global__ __launch_bounds__(256) void k_gemm128m(const _Float16* __restrict__ X,
                                                  const _Float16* __restrict__ Wp,
                                                  const float* __restrict__ bias,
                                                  const float* __restrict__ dis,
                                                  _Float16* __restrict__ out) {
    int wave = threadIdx.x >> 6, lane = threadIdx.x & 63;
    int row0 = blockIdx.x * 128 + wave * 32;
    int rA = lane & 15, kg = lane >> 4;

    f32x4 acc[2][8];
    #pragma unroll
    for (int s = 0; s < 2; ++s)
        #pragma unroll
        for (int c = 0; c < 8; ++c)
            acc[s][c] = {0.f, 0.f, 0.f, 0.f};

    int r0c = row0 + rA;      if (r0c > NN - 1) r0c = NN - 1;
    int r1c = row0 + 16 + rA; if (r1c > NN - 1) r1c = NN - 1;
    const _Float16* xp0 = X + (size_t)r0c * HID + kg * 8;
    const _Float16* xp1 = X + (size_t)r1c * HID + kg * 8;

    #pragma unroll
    for (int kb = 0; kb < 4; ++kb) {
        f16x8 a0 = *(const f16x8*)(xp0 + kb * 32);
        f16x8 a1 = *(const f16x8*)(xp1 + kb * 32);
        #pragma unroll
        for (int ct = 0; ct < 8; ++ct) {
            f16x8 b = *(const f16x8*)&Wp[(size_t)((kb * 8 + ct) * 64 + lane) * 8];
            acc[0][ct] = __builtin_amdgcn_mfma_f32_16x16x32_f16(a0, b, acc[0][ct], 0, 0, 0);
            acc[1][ct] = __builtin_amdgcn_mfma_f32_16x16x32_f16(a1, b, acc[1][ct], 0, 0, 0);
        }
    }

    int c15 = lane & 15;
    #pragma unroll
    for (int s = 0; s < 2; ++s) {
        int rbase = row0 + s * 16 + kg * 4;
        float dv[4];
        #pragma unroll
        for (int r = 0; r < 4; ++r) {
            int rr = rbase + r; if (rr > NN - 1) rr = NN - 1;
            dv[r] = dis[rr];
        }
        #pragma unroll
        for (int ct = 0; ct < 8; ++ct) {
            int col = ct * 16 + c15;
            float bb = bias[col];
            #pragma unroll
            for (int r = 0; r < 4; ++r) {
                int rr = rbase + r;
                if (rr < NN) {
                    float v = fmaxf(acc[s][ct][r] + bb, 0.f) * dv[r];
                    out[(size_t)rr * HID + col] = (_Float16)v;
                }
            }
        }
    }
}

// ---------- fused mean-pool + final linear ----------
__global__ __launch_bounds__(64) void k_poollin(const _Float16* __restrict__ H, const int* __restrict__ gstart,
                                                const float* __restrict__ Wf, const float* __restrict__ bf,
                                                float* __restrict__ out) {
    int g = blockIdx.x;
    int t = threadIdx.x;
    int beg = gstart[g], end = gstart[g + 1];
    float ax = 0.f, ay = 0.f;
    for (int n = beg; n < end; ++n) {
        ax += (float)H[(size_t)n * HID + t];
        ay += (float)H[(size_t)n * HID + 64 + t];
    }
    float inv = 1.f / fmaxf((float)(end - beg), 1.f);
    __shared__ float ps[HID];
    ps[t] = ax * inv;
    ps[t + 64] = ay * inv;
    __syncthreads();
    if (t < NC) {
        float a = bf[t];
        #pragma unroll 4
        for (int k = 0; k < HID; ++k) a += ps[k] * Wf[k * NC + t];
        out[g * NC + t] = a;
    }
}

// ---------- launch ----------

extern "C" void kernel_launch(void* const* d_in, const int* in_sizes, int n_in,
                              void* d_out, int out_size, void* d_ws, size_t ws_size,
                              hipStream_t stream) {
    const float* x   = (const float*)d_in[0];
    const int* ei    = (const int*)d_in[1];
    const int* batch = (const int*)d_in[2];
    const float* W1 = (const float*)d_in[3];
    const float* b1 = (const float*)d_in[4];
    const float* W2 = (const float*)d_in[5];
    const float* b2 = (const float*)d_in[6];
    const float* W3 = (const float*)d_in[7];
    const float* b3 = (const float*)d_in[8];
    const float* Wl = (const float*)d_in[9];
    const float* bl = (const float*)d_in[10];
    float* out = (float*)d_out;

    char* ws = (char*)d_ws;
    size_t off = 0;
    auto alloc = [&](size_t bytes) -> void* {
        void* p = ws + off;
        off += (bytes + 255) & ~(size_t)255;
        return p;
    };
    float*        dis    = (float*)alloc((size_t)NN * 4);
    unsigned int* meta   = (unsigned int*)alloc((size_t)NN * 4);
    int*          csr    = (int*)alloc((size_t)NBK * CCAP * 4);
    unsigned int* p1     = (unsigned int*)alloc((size_t)NBK * BCAP * 4);
    int*          gcur   = (int*)alloc(NBK * 4);
    int*          gstart = (int*)alloc((size_t)(NG + 1) * 4);
    _Float16*     xsc    = (_Float16*)alloc((size_t)(NN + 1) * 16 * 2);
    _Float16*     Wp2    = (_Float16*)alloc((size_t)HID * HID * 2);
    float*        Wf     = (float*)alloc((size_t)HID * NC * 4);
    float*        bf     = (float*)alloc(NC * 4);
    _Float16*     Ht     = (_Float16*)alloc((size_t)(NN + 1) * HID * 2);
    _Float16*     tb16   = (_Float16*)alloc((size_t)(NN + 1) * HID * 2);
    (void)ws_size; (void)in_sizes; (void)n_in; (void)out_size;

    hipMemsetAsync(gcur, 0, NBK * 4, stream);

    // CSR build
    k_p1scatter<<<(NE + 4095) / 4096, 1024, 0, stream>>>(ei, gcur, p1);
    k_p2fill<<<NBK, 1024, 0, stream>>>(p1, gcur, meta, csr, dis);

    // fused setup (needs dis)
    k_setup<<<6313, 256, 0, stream>>>(x, dis, batch, W2, W3, b3, Wl, bl,
                                      xsc, gstart, Wp2, Wf, bf, Ht);

    // layer 1 (fused agg + gemm) -> Ht (prescaled fp16)
    k_l1<<<NN / 16, 256, 0, stream>>>(xsc, meta, csr, dis, W1, b1, Ht);

    // layer 2: agg -> tb16, MFMA GEMM -> Ht (prescaled)
    k_agg16<<<(NN + 3) / 4, 256, 0, stream>>>(Ht, meta, csr, dis, tb16);
    k_gemm128m<<<(NN + 127) / 128, 256, 0, stream>>>(tb16, Wp2, b2, dis, Ht);

    // layer 3: agg only (W3 folded into Wf) -> tb16
    k_agg16<<<(NN + 3) / 4, 256, 0, stream>>>(Ht, meta, csr, dis, tb16);

    // pool + linear
    k_poollin<<<NG, 64, 0, stream>>>(tb16, gstart, Wf, bf, out);
}